// Round 3
// baseline (116.094 us; speedup 1.0000x reference)
//
#include <hip/hip_runtime.h>

// Signature_72327249265296: depth-4 path signature, path [64,512,10] fp32.
// out[b] = concat(A1[10], A2[100], A3[1000], A4[10000]).
//
// V3 (resubmit — round 2 failed on container acquisition, not the kernel):
// fix LDS-throughput bound. V2's loop issued ~40 LDS-pipe cycles per
// wave-step (2x ds_read_b128 + b64 broadcasts + 3x b32), and LDS is per-CU,
// so 16 waves/CU saturated the LDS pipe at ~34us regardless of occupancy.
//   - broadcast dx row (same for all 64 lanes) now comes from GLOBAL via
//     wave-uniform loads -> compiler emits s_load_dwordx4 (SMEM pipe, scalar
//     cache) -> zero LDS cost. dxP layout [64][512][12] (48B rows, 16B-aligned).
//   - per-lane indexed dx comes from a TRANSPOSED LDS tile dxT[c][s], read as
//     ds_read_b128 covering 4 steps -> 3 b128 / 4 steps ~ 9 LDS cyc/step-wave,
//     only 2-way bank aliasing (free).
//   - NSEG=8 segments x 64 steps -> 2048 blocks, 32 waves/CU (100% occ),
//     VALU-throughput-bound floor ~9us.
//   - workspace use is free: the harness poisons the full 256MB ws every
//     iteration anyway (the 42us fillBuffer in the timed graph).
// Chen per-step recurrence (unchanged):
//   p1 = A1/6 + dx_i/24 ; q1 = A1/2 + dx_i/6 ; r1 = A1 + dx_i/2
//   p2 = A2/2 + p1*dx_j ; q2 = A2 + q1*dx_j  ; A2 += r1*dx_j
//   p3 = A3 + p2*dx_k   ;                      A3 += q2*dx_k
//   A1 += dx_i          ; A4[l] += p3*dx_l
// Segment combine (Chen, levels 1-4), B = later segment:
//   Z4[ijkl] = A4 + A3[ijk]B1[l] + A2[ij]B2[kl] + A1[i]B3[jkl] + B4[ijkl]
//   Z3[ijk]  = A3 + A2[ij]B1[k] + A1[i]B2[jk] + B3[ijk]
//   Z2[ij]   = A2 + A1 B1[j] + B2[ij] ;  Z1[i] = A1 + B1[i]

#define CH      10
#define NSTEPS  511
#define SIGSZ   11110
#define WSSEG   11112                    // per-partial stride (16B-aligned)
#define NSEG    8
#define SEGLEN  64
#define PADT    68                       // LDS step-stride (272B: 2-way alias only)

// float offsets into workspace
#define PART_OFF 0                                   // [64][NSEG][WSSEG]
#define DXP_OFF  (64 * NSEG * WSSEG)                 // [64][512][12] padded rows
#define DXT_OFF  (DXP_OFF + 64 * 512 * 12)           // [64][10][512] transposed

__global__ __launch_bounds__(256)
void sig_prep(const float* __restrict__ path, float* __restrict__ dxP,
              float* __restrict__ dxT) {
    const int b   = blockIdx.x;
    const float* p = path + b * (512 * CH);
    for (int e = threadIdx.x; e < 512 * CH; e += 256) {
        const int s = e / CH;
        const int c = e - s * CH;
        const float v = (s < NSTEPS) ? (p[e + CH] - p[e]) : 0.f;  // row 511 = 0 pad
        dxP[(size_t)b * (512 * 12) + s * 12 + c] = v;
        dxT[(size_t)b * (CH * 512) + c * 512 + s] = v;
    }
}

// one 4-substep macro: broadcast row DR is wave-uniform (scalar loads)
#define STEP(DXI, DXJ, DXK, DR) do {                                   \
    const float4 d0 = *(const float4*)(DR);                            \
    const float4 d1 = *(const float4*)((DR) + 4);                      \
    const float2 d2 = *(const float2*)((DR) + 8);                      \
    const float dxi = (DXI), dxj = (DXJ), dxk = (DXK);                 \
    const float p1 = a1 * (1.f / 6.f) + dxi * (1.f / 24.f);            \
    const float q1 = a1 * 0.5f        + dxi * (1.f / 6.f);             \
    const float r1 = a1               + dxi * 0.5f;                    \
    const float p2 = a2 * 0.5f + p1 * dxj;                             \
    const float q2 = a2        + q1 * dxj;                             \
    a2 += r1 * dxj;                                                    \
    const float p3 = a3 + p2 * dxk;                                    \
    a3 += q2 * dxk;                                                    \
    a1 += dxi;                                                         \
    a4[0] += p3 * d0.x; a4[1] += p3 * d0.y;                            \
    a4[2] += p3 * d0.z; a4[3] += p3 * d0.w;                            \
    a4[4] += p3 * d1.x; a4[5] += p3 * d1.y;                            \
    a4[6] += p3 * d1.z; a4[7] += p3 * d1.w;                            \
    a4[8] += p3 * d2.x; a4[9] += p3 * d2.y;                            \
} while (0)

__global__ __launch_bounds__(256)
void sig_partial(const float* __restrict__ dxP, const float* __restrict__ dxT,
                 float* __restrict__ ws) {
    __shared__ __align__(16) float tl[CH * PADT];

    const int tid  = threadIdx.x;
    const int bx   = blockIdx.x;          // 2048 blocks
    const int b    = bx >> 5;             // batch 0..63
    const int seg  = (bx >> 2) & 7;       // segment 0..7
    const int part = bx & 3;              // chain slice 0..3
    const int s0   = seg * SEGLEN;

    // stage transposed segment slice [10][64] into LDS (coalesced, linear-ish)
    for (int e = tid; e < CH * SEGLEN; e += 256) {
        const int c = e >> 6;             // 0..9
        const int s = e & 63;
        tl[c * PADT + s] = dxT[(size_t)(b * CH + c) * 512 + s0 + s];
    }
    __syncthreads();

    const int id = part * 256 + tid;      // chain id = i*100 + j*10 + k
    if (id < 1000) {
        const int ci = id / 100;
        const int cj = (id / 10) % 10;
        const int ck = id % 10;

        float a1 = 0.f, a2 = 0.f, a3 = 0.f;
        float a4[10];
        #pragma unroll
        for (int l = 0; l < 10; ++l) a4[l] = 0.f;

        const float* ti = tl + ci * PADT;
        const float* tj = tl + cj * PADT;
        const float* tk = tl + ck * PADT;
        const float* dp = dxP + (size_t)(b * 512 + s0) * 12;  // uniform

        #pragma unroll 2
        for (int s4 = 0; s4 < SEGLEN; s4 += 4) {
            const float4 vi = *(const float4*)(ti + s4);
            const float4 vj = *(const float4*)(tj + s4);
            const float4 vk = *(const float4*)(tk + s4);
            const float* dr = dp + s4 * 12;
            STEP(vi.x, vj.x, vk.x, dr);
            STEP(vi.y, vj.y, vk.y, dr + 12);
            STEP(vi.z, vj.z, vk.z, dr + 24);
            STEP(vi.w, vj.w, vk.w, dr + 36);
        }

        // write this chain's share of the segment partial
        float* ob = ws + (size_t)(b * NSEG + seg) * WSSEG;
        float* o4 = ob + 1110 + id * 10;
        #pragma unroll
        for (int l = 0; l < 10; ++l) o4[l] = a4[l];
        ob[110 + id] = a3;
        if (ck == 0)            ob[10 + ci * 10 + cj] = a2;
        if (ck == 0 && cj == 0) ob[ci] = a1;
    }
}

__global__ __launch_bounds__(256)
void sig_combine(const float* __restrict__ ws, float* __restrict__ out) {
    __shared__ float B[1110];             // levels 1-3 of one segment partial

    const int tid  = threadIdx.x;
    const int b    = blockIdx.x >> 2;
    const int part = blockIdx.x & 3;
    const int id   = part * 256 + tid;
    const bool valid = (id < 1000);

    const int ci = id / 100;
    const int cj = (id / 10) % 10;
    const int ck = id % 10;

    const float* w0 = ws + (size_t)b * NSEG * WSSEG;

    float a1 = 0.f, a2 = 0.f, a3 = 0.f;
    float a4[10];
    #pragma unroll
    for (int l = 0; l < 10; ++l) a4[l] = 0.f;
    if (valid) {
        a1 = w0[ci];
        a2 = w0[10 + ci * 10 + cj];
        a3 = w0[110 + id];
        #pragma unroll
        for (int l = 0; l < 10; ++l) a4[l] = w0[1110 + id * 10 + l];
    }

    for (int s = 1; s < NSEG; ++s) {
        const float* wb = w0 + (size_t)s * WSSEG;
        // cooperative load of levels 1-3 (1110 floats) into LDS
        __syncthreads();                  // previous iter done reading B
        for (int e = tid; e < 1110; e += 256) B[e] = wb[e];
        __syncthreads();

        if (valid) {
            const float b1i   = B[ci];
            const float b1j   = B[cj];
            const float b1k   = B[ck];
            const float b2_ij = B[10 + ci * 10 + cj];
            const float b2_jk = B[10 + cj * 10 + ck];
            const float b3ijk = B[110 + id];

            float b4v[10];
            #pragma unroll
            for (int l = 0; l < 10; ++l) b4v[l] = wb[1110 + id * 10 + l];

            // Z4 uses OLD a1,a2,a3 (computed before lower levels update)
            #pragma unroll
            for (int l = 0; l < 10; ++l)
                a4[l] += a3 * B[l] + a2 * B[10 + ck * 10 + l]
                       + a1 * B[110 + (cj * 10 + ck) * 10 + l] + b4v[l];
            a3 += a2 * b1k + a1 * b2_jk + b3ijk;
            a2 += a1 * b1j + b2_ij;
            a1 += b1i;
        }
    }

    if (valid) {
        float* ob = out + (size_t)b * SIGSZ;
        float* o4 = ob + 1110 + id * 10;
        #pragma unroll
        for (int l = 0; l < 10; ++l) o4[l] = a4[l];
        ob[110 + id] = a3;
        if (ck == 0)            ob[10 + ci * 10 + cj] = a2;
        if (ck == 0 && cj == 0) ob[ci] = a1;
    }
}

extern "C" void kernel_launch(void* const* d_in, const int* in_sizes, int n_in,
                              void* d_out, int out_size, void* d_ws, size_t ws_size,
                              hipStream_t stream) {
    const float* path = (const float*)d_in[0];   // [64, 512, 10] fp32
    float* out = (float*)d_out;                  // [64, 11110] fp32
    float* ws  = (float*)d_ws;                   // needs ~25.7 MB

    float* part = ws + PART_OFF;
    float* dxP  = ws + DXP_OFF;
    float* dxT  = ws + DXT_OFF;

    sig_prep   <<<dim3(64),   dim3(256), 0, stream>>>(path, dxP, dxT);
    sig_partial<<<dim3(2048), dim3(256), 0, stream>>>(dxP, dxT, part);
    sig_combine<<<dim3(256),  dim3(256), 0, stream>>>(part, out);
}

// Round 4
// 97.360 us; speedup vs baseline: 1.1924x; 1.1924x over previous
//
#include <hip/hip_runtime.h>

// Signature_72327249265296: depth-4 path signature, path [64,512,10] fp32.
// out[b] = concat(A1[10], A2[100], A3[1000], A4[10000]).
//
// V4: multi-chain threads to beat the LDS broadcast wall.
// V2 measurement: broadcast ds_read costs full RF-fill BW (~12cy/b128/wave
// even when all lanes read the same address) -> 40 LDS-cyc/step/wave -> 34us.
// Total broadcast traffic = 1.31GB / (chains per thread). Fix: each thread
// owns (i,j) x 5 k's (a k-half):
//   - d row (10 floats) loaded once per step serves BOTH the A4 broadcast
//     and dx_k for all 5 owned k's (selected via if-constexpr half, no
//     runtime reg indexing, no divergence: half bit is wave-uniform tid>>7).
//   - shared Horner prefix (p1,q1,r1,p2,q2,a2,a1 on (i,j)) amortizes over
//     5 chains: ~70 VALU inst/step/thread vs 5x22 naive.
//   - LDS/step/wave ~36cy serving 5 chains; VALU 140cy/step/wave.
//     Grid 512 blocks x 4 waves = 8 waves/CU (exactly 2 blocks/CU):
//     VALU ~7.5us, LDS ~7.7us -> balanced, partial ~9us.
//   - dx staged in-kernel straight from path (2.6KB/block) in two LDS
//     layouts: rowL[64][12] (broadcast float4) + trL[10][68] (per-lane
//     float4 over 4 steps). No prep kernel, no global dx arrays (V3's
//     sig_prep had 64 blocks of stride-2KB scattered writes).
// Chen per-step recurrence per chain (i,j,k) (validated V1/V2):
//   p1 = A1/6 + dxi/24 ; q1 = A1/2 + dxi/6 ; r1 = A1 + dxi/2
//   p2 = A2/2 + p1*dxj ; q2 = A2 + q1*dxj  ; A2 += r1*dxj
//   p3k = A3k + p2*dk  ; A3k += q2*dk      ; A1 += dxi
//   A4[k][l] += p3k*d[l]
// Segment combine (validated V2/V3, NSEG=8): Chen fold of 8 partials.

#define CH      10
#define NSTEPS  511
#define SIGSZ   11110
#define WSSEG   11112                    // per-partial stride (16B-aligned)
#define NSEG    8
#define SEGLEN  64
#define TRP     68                       // transposed LDS stride (2-way alias only)

__global__ __launch_bounds__(256)
void sig_partial(const float* __restrict__ path, float* __restrict__ ws) {
    __shared__ __align__(16) float rowL[SEGLEN * 12];   // [s][c] padded rows
    __shared__ __align__(16) float trL[CH * TRP];       // [c][s] transposed

    const int tid = threadIdx.x;
    const int bx  = blockIdx.x;          // 512 blocks = 64 batches x 8 segments
    const int b   = bx >> 3;
    const int seg = bx & 7;
    const int s0  = seg * SEGLEN;

    // ---- stage this segment's increments into both LDS layouts ----
    const float* p = path + (size_t)b * (512 * CH) + s0 * CH;
    for (int e = tid; e < SEGLEN * CH; e += 256) {
        const int s = e / CH;
        const int c = e - s * CH;
        float v = 0.f;
        if (s0 + s < NSTEPS) v = p[e + CH] - p[e];   // guarded: no OOB speculation
        rowL[s * 12 + c] = v;
        trL[c * TRP + s] = v;
    }
    __syncthreads();

    // thread -> (i,j, k-half): tid 0..99 -> half 0, tid 128..227 -> half 1.
    // half = tid>>7 is wave-uniform (waves 0,1 vs waves 2,3).
    const int half = tid >> 7;
    const int ij   = tid & 127;
    if (ij < 100) {
        const int ci = ij / 10;
        const int cj = ij - ci * 10;

        float a1 = 0.f, a2 = 0.f;
        float a3[5];
        float a4[5][10];
        #pragma unroll
        for (int m = 0; m < 5; ++m) {
            a3[m] = 0.f;
            #pragma unroll
            for (int l = 0; l < 10; ++l) a4[m][l] = 0.f;
        }

        const float* ti = trL + ci * TRP;
        const float* tj = trL + cj * TRP;

        auto run = [&](auto hc) {
            constexpr int H = decltype(hc)::value;
            for (int s4 = 0; s4 < SEGLEN; s4 += 4) {
                const float4 vi = *(const float4*)(ti + s4);
                const float4 vj = *(const float4*)(tj + s4);
                const float* rp = rowL + s4 * 12;
                #pragma unroll
                for (int u = 0; u < 4; ++u) {
                    const float4 d0 = *(const float4*)(rp + u * 12);
                    const float4 d1 = *(const float4*)(rp + u * 12 + 4);
                    const float2 d2 = *(const float2*)(rp + u * 12 + 8);
                    const float dxi = (u == 0) ? vi.x : (u == 1) ? vi.y
                                     : (u == 2) ? vi.z : vi.w;
                    const float dxj = (u == 0) ? vj.x : (u == 1) ? vj.y
                                     : (u == 2) ? vj.z : vj.w;

                    // shared (i,j) prefix
                    const float p1 = a1 * (1.f / 6.f) + dxi * (1.f / 24.f);
                    const float q1 = a1 * 0.5f        + dxi * (1.f / 6.f);
                    const float r1 = a1               + dxi * 0.5f;
                    const float p2 = a2 * 0.5f + p1 * dxj;
                    const float q2 = a2        + q1 * dxj;
                    a2 += r1 * dxj;
                    a1 += dxi;

                    // this half's 5 k-values, selected at compile time
                    const float dk0 = H ? d1.y : d0.x;
                    const float dk1 = H ? d1.z : d0.y;
                    const float dk2 = H ? d1.w : d0.z;
                    const float dk3 = H ? d2.x : d0.w;
                    const float dk4 = H ? d2.y : d1.x;

                    const float p30 = a3[0] + p2 * dk0;  a3[0] += q2 * dk0;
                    const float p31 = a3[1] + p2 * dk1;  a3[1] += q2 * dk1;
                    const float p32 = a3[2] + p2 * dk2;  a3[2] += q2 * dk2;
                    const float p33 = a3[3] + p2 * dk3;  a3[3] += q2 * dk3;
                    const float p34 = a3[4] + p2 * dk4;  a3[4] += q2 * dk4;

                    #pragma unroll
                    for (int m = 0; m < 5; ++m) {
                        const float p3 = (m == 0) ? p30 : (m == 1) ? p31
                                        : (m == 2) ? p32 : (m == 3) ? p33 : p34;
                        a4[m][0] += p3 * d0.x; a4[m][1] += p3 * d0.y;
                        a4[m][2] += p3 * d0.z; a4[m][3] += p3 * d0.w;
                        a4[m][4] += p3 * d1.x; a4[m][5] += p3 * d1.y;
                        a4[m][6] += p3 * d1.z; a4[m][7] += p3 * d1.w;
                        a4[m][8] += p3 * d2.x; a4[m][9] += p3 * d2.y;
                    }
                }
            }
        };
        if (half == 0) run(std::integral_constant<int, 0>{});
        else           run(std::integral_constant<int, 1>{});

        // ---- epilogue: write this thread's share of the segment partial ----
        const int k0 = half * 5;
        float* ob = ws + (size_t)(b * NSEG + seg) * WSSEG;
        #pragma unroll
        for (int m = 0; m < 5; ++m) {
            const int id = ci * 100 + cj * 10 + k0 + m;
            float* o4 = ob + 1110 + id * 10;
            #pragma unroll
            for (int l = 0; l < 10; ++l) o4[l] = a4[m][l];
            ob[110 + id] = a3[m];
        }
        if (half == 0)            ob[10 + ci * 10 + cj] = a2;
        if (half == 0 && cj == 0) ob[ci] = a1;
    }
}

__global__ __launch_bounds__(256)
void sig_combine(const float* __restrict__ ws, float* __restrict__ out) {
    __shared__ float B[1110];             // levels 1-3 of one segment partial

    const int tid  = threadIdx.x;
    const int b    = blockIdx.x >> 2;
    const int part = blockIdx.x & 3;
    const int id   = part * 256 + tid;
    const bool valid = (id < 1000);

    const int ci = id / 100;
    const int cj = (id / 10) % 10;
    const int ck = id % 10;

    const float* w0 = ws + (size_t)b * NSEG * WSSEG;

    float a1 = 0.f, a2 = 0.f, a3 = 0.f;
    float a4[10];
    #pragma unroll
    for (int l = 0; l < 10; ++l) a4[l] = 0.f;
    if (valid) {
        a1 = w0[ci];
        a2 = w0[10 + ci * 10 + cj];
        a3 = w0[110 + id];
        #pragma unroll
        for (int l = 0; l < 10; ++l) a4[l] = w0[1110 + id * 10 + l];
    }

    for (int s = 1; s < NSEG; ++s) {
        const float* wb = w0 + (size_t)s * WSSEG;
        __syncthreads();                  // previous iter done reading B
        for (int e = tid; e < 1110; e += 256) B[e] = wb[e];
        __syncthreads();

        if (valid) {
            const float b1i   = B[ci];
            const float b1j   = B[cj];
            const float b1k   = B[ck];
            const float b2_ij = B[10 + ci * 10 + cj];
            const float b2_jk = B[10 + cj * 10 + ck];
            const float b3ijk = B[110 + id];

            float b4v[10];
            #pragma unroll
            for (int l = 0; l < 10; ++l) b4v[l] = wb[1110 + id * 10 + l];

            // Z4 uses OLD a1,a2,a3 (computed before lower levels update)
            #pragma unroll
            for (int l = 0; l < 10; ++l)
                a4[l] += a3 * B[l] + a2 * B[10 + ck * 10 + l]
                       + a1 * B[110 + (cj * 10 + ck) * 10 + l] + b4v[l];
            a3 += a2 * b1k + a1 * b2_jk + b3ijk;
            a2 += a1 * b1j + b2_ij;
            a1 += b1i;
        }
    }

    if (valid) {
        float* ob = out + (size_t)b * SIGSZ;
        float* o4 = ob + 1110 + id * 10;
        #pragma unroll
        for (int l = 0; l < 10; ++l) o4[l] = a4[l];
        ob[110 + id] = a3;
        if (ck == 0)            ob[10 + ci * 10 + cj] = a2;
        if (ck == 0 && cj == 0) ob[ci] = a1;
    }
}

extern "C" void kernel_launch(void* const* d_in, const int* in_sizes, int n_in,
                              void* d_out, int out_size, void* d_ws, size_t ws_size,
                              hipStream_t stream) {
    const float* path = (const float*)d_in[0];   // [64, 512, 10] fp32
    float* out = (float*)d_out;                  // [64, 11110] fp32
    float* ws  = (float*)d_ws;                   // 64*8*11112 floats = 22.8 MB

    sig_partial<<<dim3(512), dim3(256), 0, stream>>>(path, ws);
    sig_combine<<<dim3(256), dim3(256), 0, stream>>>(ws, out);
}